// Round 9
// baseline (272.242 us; speedup 1.0000x reference)
//
#include <hip/hip_runtime.h>

// B=8, N=2048, DIN=DOUT=128, DA=2, NEG_SLOPE=0.2
// out[b,i,:] = sum_j mask[b,i,j]*w[b,j]*xv[b,j,:] / sum_j mask[b,i,j]*w[b,j]
//   w[b,j]  = exp( leaky(x@Wc[0])*Wcat[2] + leaky(x@Wc[1])*Wcat[3] )  (lr_row cancels)
//   xv      = x @ Wx^T + bx
// k-order permutation sigma (from ballot packing): MFMA k-slot (G,j) holds
// logical col t*32 + 4j + G. Applied consistently to: mask bits (pack),
// u B-fragments (prep scatter), wcol (prep), unpack+denominator (attn).

typedef __bf16 bf16x8 __attribute__((ext_vector_type(8)));
typedef float  f32x4  __attribute__((ext_vector_type(4)));
typedef int    i32x4  __attribute__((ext_vector_type(4)));
typedef unsigned int u32;
typedef unsigned long long u64;

#define MFMA_BF16(a, b, c) __builtin_amdgcn_mfma_f32_16x16x32_bf16((a), (b), (c), 0, 0, 0)

// async global->LDS; HW writes lane l at lds_base + l*16 (wave-uniform base).
#define GLOAD_LDS16(gp, lp)                                                     \
  __builtin_amdgcn_global_load_lds(                                             \
      (const __attribute__((address_space(1))) void*)(gp),                      \
      (__attribute__((address_space(3))) void*)(lp), 16, 0, 0)

static __device__ __forceinline__ bf16x8 cvt8(f32x4 a, f32x4 b) {
  bf16x8 r;
  r[0] = (__bf16)a[0]; r[1] = (__bf16)a[1]; r[2] = (__bf16)a[2]; r[3] = (__bf16)a[3];
  r[4] = (__bf16)b[0]; r[5] = (__bf16)b[1]; r[6] = (__bf16)b[2]; r[7] = (__bf16)b[3];
  return r;
}

// ---------------------------------------------------------------------------
// Kernel A: w[k] -> wcol (sigma order), u[k][c] = w[k]*xv[k][c] in sigma'd
// mfma_16x16x32 B-fragment order: tile elem (lane = Gf*16+np, j') holds
// col np of logical k with k%32 = 4j'+Gf.  flat: (((b*64+t)*8+n)*64+lane)*8+j
// ---------------------------------------------------------------------------
__global__ __launch_bounds__(256) void prep_kernel(
    const float* __restrict__ x, const float* __restrict__ Wc,
    const float* __restrict__ Wcat, const float* __restrict__ Wx,
    const float* __restrict__ bx, __bf16* __restrict__ u,
    __bf16* __restrict__ wcol)
{
  __shared__ __bf16 lds[8192];  // 16 KB: 2 t-steps x 8 tiles x 512
  const int blk = blockIdx.x;            // 256 blocks
  const int b = blk >> 5, mt = blk & 31; // 32 blocks/batch, 64 rows each
  const int wv = threadIdx.x >> 6, lane = threadIdx.x & 63;
  const int np = lane & 15, G = lane >> 4;
  const int r0 = mt * 64 + wv * 16;      // wave's 16 k-rows

  const float* xp = x + ((size_t)(b * 2048 + r0 + np)) * 128 + G * 8;
  bf16x8 af[4];
#pragma unroll
  for (int kk = 0; kk < 4; ++kk) {
    f32x4 x0 = *(const f32x4*)(xp + kk * 32);
    f32x4 x1 = *(const f32x4*)(xp + kk * 32 + 4);
    af[kk] = cvt8(x0, x1);
  }

  f32x4 acc[8], accC;
#pragma unroll
  for (int n = 0; n < 8; ++n) { acc[n][0] = 0.f; acc[n][1] = 0.f; acc[n][2] = 0.f; acc[n][3] = 0.f; }
  accC[0] = accC[1] = accC[2] = accC[3] = 0.f;

#pragma unroll
  for (int n = 0; n < 8; ++n) {
    const float* wp = Wx + (n * 16 + np) * 128 + G * 8;
#pragma unroll
    for (int kk = 0; kk < 4; ++kk) {
      f32x4 w0 = *(const f32x4*)(wp + kk * 32);
      f32x4 w1 = *(const f32x4*)(wp + kk * 32 + 4);
      acc[n] = MFMA_BF16(af[kk], cvt8(w0, w1), acc[n]);
    }
  }
#pragma unroll
  for (int kk = 0; kk < 4; ++kk) {
    bf16x8 bf;
    if (np < 2) {
      const float* cp = Wc + np * 128 + kk * 32 + G * 8;
      f32x4 c0 = *(const f32x4*)cp;
      f32x4 c1 = *(const f32x4*)(cp + 4);
      bf = cvt8(c0, c1);
    } else {
#pragma unroll
      for (int j = 0; j < 8; ++j) bf[j] = (__bf16)0.0f;
    }
    accC = MFMA_BF16(af[kk], bf, accC);
  }

  const float a20 = Wcat[2], a21 = Wcat[3];
  float wexp[4];
#pragma unroll
  for (int r = 0; r < 4; ++r) {
    float c0 = __shfl(accC[r], lane & 48);
    float c1 = __shfl(accC[r], (lane & 48) | 1);
    c0 = c0 > 0.f ? c0 : 0.2f * c0;
    c1 = c1 > 0.f ? c1 : 0.2f * c1;
    wexp[r] = __expf(c0 * a20 + c1 * a21);
  }

  // sigma'd wcol: w[k] (k%32 = 16(wv&1)+4G+r) -> idx t*32 + r*8 + 4(wv&1)+G
  if (np == 0) {
    const int t = mt * 2 + (wv >> 1);
#pragma unroll
    for (int r = 0; r < 4; ++r)
      wcol[(size_t)b * 2048 + t * 32 + r * 8 + 4 * (wv & 1) + G] = (__bf16)wexp[r];
  }

  // sigma'd scatter: value for k (k%32 = 16(wv&1)+4G+r) goes to fragment
  // slot (Gf=r, j' = 4(wv&1)+G): elem (r*16+np)*8 + j'
  const int t_rel = wv >> 1;
  const int jp = 4 * (wv & 1) + G;
#pragma unroll
  for (int n = 0; n < 8; ++n) {
    float bxv = bx[n * 16 + np];
#pragma unroll
    for (int r = 0; r < 4; ++r)
      lds[(t_rel * 8 + n) * 512 + (r * 16 + np) * 8 + jp] =
          (__bf16)(wexp[r] * (acc[n][r] + bxv));
  }
  __syncthreads();
  __bf16* dst = u + ((size_t)(b * 64 + mt * 2)) * 4096;
#pragma unroll
  for (int it = 0; it < 4; ++it) {
    int s = it * 256 + threadIdx.x;
    ((i32x4*)dst)[s] = ((const i32x4*)lds)[s];
  }
}

// ---------------------------------------------------------------------------
// Kernel P: mask (i32 0/1) -> bit dwords, layout per (b, rt-block of 32 rows):
//   dword[t*32 + row], byte e bit i = mask[row0+row][t*32 + 4i + e]  (sigma)
// Fully coalesced 1 KB wave reads + __ballot; 134 MB -> 4.2 MB.
// ---------------------------------------------------------------------------
__global__ __launch_bounds__(256) void pack_kernel(
    const int* __restrict__ mask, u32* __restrict__ bits)
{
  const int b = blockIdx.x & 7, rt = blockIdx.x >> 3;  // 8 x 64 (match attn)
  const int wv = threadIdx.x >> 6, lane = threadIdx.x & 63;
  const int* mbase = mask + ((size_t)b * 2048 + rt * 32) * 2048;
  u32* obase = bits + (size_t)(b * 64 + rt) * 2048;
  const int sh = (lane & 7) * 8;

  for (int r8 = 0; r8 < 8; ++r8) {
    const int row = wv * 8 + r8;
    const int* rp = mbase + (size_t)row * 2048;
#pragma unroll
    for (int c = 0; c < 8; ++c) {
      i32x4 v = *(const i32x4*)(rp + c * 256 + lane * 4);
      u64 b0 = __ballot(v[0] != 0);
      u64 b1 = __ballot(v[1] != 0);
      u64 b2 = __ballot(v[2] != 0);
      u64 b3 = __ballot(v[3] != 0);
      u32 d = (u32)((b0 >> sh) & 0xFF) | ((u32)((b1 >> sh) & 0xFF) << 8) |
              ((u32)((b2 >> sh) & 0xFF) << 16) | ((u32)((b3 >> sh) & 0xFF) << 24);
      if (lane < 8) obase[(c * 8 + lane) * 32 + row] = d;
    }
  }
}

// ---------------------------------------------------------------------------
// Kernel B v9: K-loop external traffic = u only (L2-resident). Block's whole
// mask = 8 KB of bits, staged into LDS ONCE; per-iter A-frag = 1 byte LDS
// read ([t][row] layout: np->distinct banks, G->same-dword broadcast) + unpack.
// u: R8's counted-vmcnt ring (4 bufs, uniform 2 gload_lds/wave/stage,
// vmcnt(4) steady state, never 0 until tail). Denominator in VALU from
// sigma'd wcol. 44 KB LDS -> 2 blocks/CU, 2 waves/SIMD.
// ---------------------------------------------------------------------------
__global__ __launch_bounds__(256) void attn_kernel(
    const __bf16* __restrict__ u, const __bf16* __restrict__ wcol,
    const u32* __restrict__ bits, float* __restrict__ out)
{
  __shared__ char smem[4 * 8192 + 8192 + 4096];  // ring 32K + bits 8K + w 4K
  char* bitlds = smem + 32768;
  char* wlds = smem + 40960;
  const int b = blockIdx.x & 7, rt = blockIdx.x >> 3;  // 8 x 64
  const int wv = threadIdx.x >> 6, lane = threadIdx.x & 63;
  const int np = lane & 15, G = lane >> 4;
  const int row0 = rt * 32;
  const int n0 = wv * 2, n1 = n0 + 1;

  const char* gu = (const char*)u + (size_t)b * 64 * 8192;
  const char* gw = (const char*)(wcol + (size_t)b * 2048);
  const char* gbits = (const char*)(bits + (size_t)(b * 64 + rt) * 2048);

  f32x4 acc[2][2];
#pragma unroll
  for (int mi = 0; mi < 2; ++mi)
#pragma unroll
    for (int n = 0; n < 2; ++n) { acc[mi][n][0] = 0.f; acc[mi][n][1] = 0.f; acc[mi][n][2] = 0.f; acc[mi][n][3] = 0.f; }
  float den[2] = {0.f, 0.f};

#define STAGE(it, nb)                                                          \
  do {                                                                         \
    char* dst = smem + (nb) * 8192;                                            \
    const char* src = gu + (size_t)(it) * 8192 + lane * 16;                    \
    GLOAD_LDS16(src + (2 * wv) * 1024, dst + (2 * wv) * 1024);                 \
    GLOAD_LDS16(src + (2 * wv + 1) * 1024, dst + (2 * wv + 1) * 1024);         \
  } while (0)

#define CONSUME(it, nb)                                                        \
  do {                                                                         \
    const char* ub = smem + (nb) * 8192;                                       \
    bf16x8 W = *(const bf16x8*)(wlds + (it) * 64 + G * 16);                    \
    float wf[8];                                                               \
    _Pragma("unroll")                                                          \
    for (int j = 0; j < 8; ++j) wf[j] = (float)W[j];                           \
    bf16x8 U0 = *(const bf16x8*)(ub + n0 * 1024 + lane * 16);                  \
    bf16x8 U1 = *(const bf16x8*)(ub + n1 * 1024 + lane * 16);                  \
    _Pragma("unroll")                                                          \
    for (int mi = 0; mi < 2; ++mi) {                                           \
      u32 m8 = (u32)(unsigned char)bitlds[(it) * 128 + (mi * 16 + np) * 4 + G];\
      union { u32 w[4]; bf16x8 v; } A;                                         \
      A.w[0] = ((m8 & 1u) ? 0x3F80u : 0u) | ((m8 & 2u) ? 0x3F800000u : 0u);    \
      A.w[1] = ((m8 & 4u) ? 0x3F80u : 0u) | ((m8 & 8u) ? 0x3F800000u : 0u);    \
      A.w[2] = ((m8 & 16u) ? 0x3F80u : 0u) | ((m8 & 32u) ? 0x3F800000u : 0u);  \
      A.w[3] = ((m8 & 64u) ? 0x3F80u : 0u) | ((m8 & 128u) ? 0x3F800000u : 0u); \
      float d = den[mi];                                                       \
      d += (m8 & 1u) ? wf[0] : 0.f;  d += (m8 & 2u) ? wf[1] : 0.f;             \
      d += (m8 & 4u) ? wf[2] : 0.f;  d += (m8 & 8u) ? wf[3] : 0.f;             \
      d += (m8 & 16u) ? wf[4] : 0.f; d += (m8 & 32u) ? wf[5] : 0.f;            \
      d += (m8 & 64u) ? wf[6] : 0.f; d += (m8 & 128u) ? wf[7] : 0.f;           \
      den[mi] = d;                                                             \
      acc[mi][0] = MFMA_BF16(A.v, U0, acc[mi][0]);                             \
      acc[mi][1] = MFMA_BF16(A.v, U1, acc[mi][1]);                             \
    }                                                                          \
  } while (0)

  // prologue: bits (2/wave) + w (1/wave) + ring stages 0,1,2 (6/wave) = 9
  GLOAD_LDS16(gbits + (2 * wv) * 1024 + lane * 16, bitlds + (2 * wv) * 1024);
  GLOAD_LDS16(gbits + (2 * wv + 1) * 1024 + lane * 16, bitlds + (2 * wv + 1) * 1024);
  GLOAD_LDS16(gw + wv * 1024 + lane * 16, wlds + wv * 1024);
  STAGE(0, 0); STAGE(1, 1); STAGE(2, 2);

  // steady state: vmcnt(4) = {bits,w,stage(it)} retired, 2 stages in flight
  for (int it = 0; it <= 60; ++it) {
    asm volatile("s_waitcnt vmcnt(4)" ::: "memory");
    __builtin_amdgcn_s_barrier();
    CONSUME(it, it & 3);
    STAGE(it + 3, (it + 3) & 3);
  }
  asm volatile("s_waitcnt vmcnt(4)" ::: "memory");
  __builtin_amdgcn_s_barrier();
  CONSUME(61, 1);
  asm volatile("s_waitcnt vmcnt(2)" ::: "memory");
  __builtin_amdgcn_s_barrier();
  CONSUME(62, 2);
  asm volatile("s_waitcnt vmcnt(0)" ::: "memory");
  __builtin_amdgcn_s_barrier();
  CONSUME(63, 3);
#undef STAGE
#undef CONSUME

  // epilogue: den reduce over G-groups; D row = mi*16+4G+r, col = n*16+np
#pragma unroll
  for (int mi = 0; mi < 2; ++mi) {
    float dr = den[mi] + __shfl_xor(den[mi], 16);
    dr += __shfl_xor(dr, 32);
#pragma unroll
    for (int r = 0; r < 4; ++r) {
      float dv = __shfl(dr, 4 * G + r);
      float inv = 1.0f / dv;
      float* op = out + ((size_t)b * 2048 + row0 + mi * 16 + 4 * G + r) * 128 + np;
      op[n0 * 16] = acc[mi][0][r] * inv;
      op[n1 * 16] = acc[mi][1][r] * inv;
    }
  }
}

extern "C" void kernel_launch(void* const* d_in, const int* in_sizes, int n_in,
                              void* d_out, int out_size, void* d_ws, size_t ws_size,
                              hipStream_t stream) {
  const float* x    = (const float*)d_in[0];
  const int*   mask = (const int*)d_in[1];
  // d_in[2] = Wr : unused (lr_row cancels in softmax over j)
  const float* Wc   = (const float*)d_in[3];
  const float* Wcat = (const float*)d_in[4];
  const float* Wx   = (const float*)d_in[5];
  const float* bx   = (const float*)d_in[6];
  float* out = (float*)d_out;

  // workspace: u 4 MB | wcol 32 KB | bits 4.2 MB
  const size_t U_BYTES = (size_t)8 * 64 * 4096 * 2;
  const size_t W_BYTES = (size_t)8 * 2048 * 2;
  const size_t B_BYTES = (size_t)8 * 64 * 2048 * 4;
  if (ws_size < U_BYTES + W_BYTES + B_BYTES) return;
  __bf16* u    = (__bf16*)d_ws;
  __bf16* wcol = (__bf16*)((char*)d_ws + U_BYTES);
  u32*    bits = (u32*)((char*)d_ws + U_BYTES + W_BYTES);

  prep_kernel<<<256, 256, 0, stream>>>(x, Wc, Wcat, Wx, bx, u, wcol);
  pack_kernel<<<512, 256, 0, stream>>>(mask, bits);
  attn_kernel<<<512, 256, 0, stream>>>(u, wcol, bits, out);
}

// Round 10
// 251.301 us; speedup vs baseline: 1.0833x; 1.0833x over previous
//
#include <hip/hip_runtime.h>

// B=8, N=2048, DIN=DOUT=128, DA=2, NEG_SLOPE=0.2
// out[b,i,:] = sum_j mask[b,i,j]*w[b,j]*xv[b,j,:] / sum_j mask[b,i,j]*w[b,j]
//   w[b,j]  = exp( leaky(x@Wc[0])*Wcat[2] + leaky(x@Wc[1])*Wcat[3] )  (lr_row cancels)
//   xv      = x @ Wx^T + bx
// u: 9 B-fragment tiles per 32-k t-step (R7 verified layout; tile8 col0 = w).
// Abuf: mask as bf16 {1,0} in exact mfma A-fragment order (R10 new).

typedef __bf16 bf16x8 __attribute__((ext_vector_type(8)));
typedef float  f32x4  __attribute__((ext_vector_type(4)));
typedef int    i32x4  __attribute__((ext_vector_type(4)));
typedef unsigned int u32;

#define MFMA_BF16(a, b, c) __builtin_amdgcn_mfma_f32_16x16x32_bf16((a), (b), (c), 0, 0, 0)

// async global->LDS; HW writes lane l at lds_base + l*16 (wave-uniform base).
#define GLOAD_LDS16(gp, lp)                                                     \
  __builtin_amdgcn_global_load_lds(                                             \
      (const __attribute__((address_space(1))) void*)(gp),                      \
      (__attribute__((address_space(3))) void*)(lp), 16, 0, 0)

static __device__ __forceinline__ bf16x8 cvt8(f32x4 a, f32x4 b) {
  bf16x8 r;
  r[0] = (__bf16)a[0]; r[1] = (__bf16)a[1]; r[2] = (__bf16)a[2]; r[3] = (__bf16)a[3];
  r[4] = (__bf16)b[0]; r[5] = (__bf16)b[1]; r[6] = (__bf16)b[2]; r[7] = (__bf16)b[3];
  return r;
}

// ---------------------------------------------------------------------------
// Kernel A (verified R6/R7): per (b, 64 k-rows): w[k], xv[k][c]; u pre-swizzled
// in mfma_16x16x32 B-fragment order, 9 tiles per t-step:
//   n<8: elem(b,t,n,lane,j) = w[k]*xv[k][n*16+np],  k = t*32+(lane>>4)*8+j
//   n=8: elem = (np==0) ? w[k] : 0    (denominator column)
// flat index (((b*64+t)*9+n)*64+lane)*8+j
// ---------------------------------------------------------------------------
__global__ __launch_bounds__(256) void prep_kernel(
    const float* __restrict__ x, const float* __restrict__ Wc,
    const float* __restrict__ Wcat, const float* __restrict__ Wx,
    const float* __restrict__ bx, __bf16* __restrict__ u)
{
  __shared__ __bf16 lds[9216];  // 18 KB: 2 t-steps x 9 tiles x 512
  const int blk = blockIdx.x;            // 256 blocks
  const int b = blk >> 5, mt = blk & 31; // 32 blocks/batch, 64 rows each
  const int wv = threadIdx.x >> 6, lane = threadIdx.x & 63;
  const int np = lane & 15, G = lane >> 4;
  const int r0 = mt * 64 + wv * 16;      // wave's 16 k-rows

  const float* xp = x + ((size_t)(b * 2048 + r0 + np)) * 128 + G * 8;
  bf16x8 af[4];
#pragma unroll
  for (int kk = 0; kk < 4; ++kk) {
    f32x4 x0 = *(const f32x4*)(xp + kk * 32);
    f32x4 x1 = *(const f32x4*)(xp + kk * 32 + 4);
    af[kk] = cvt8(x0, x1);
  }

  f32x4 acc[8], accC;
#pragma unroll
  for (int n = 0; n < 8; ++n) { acc[n][0] = 0.f; acc[n][1] = 0.f; acc[n][2] = 0.f; acc[n][3] = 0.f; }
  accC[0] = accC[1] = accC[2] = accC[3] = 0.f;

#pragma unroll
  for (int n = 0; n < 8; ++n) {
    const float* wp = Wx + (n * 16 + np) * 128 + G * 8;
#pragma unroll
    for (int kk = 0; kk < 4; ++kk) {
      f32x4 w0 = *(const f32x4*)(wp + kk * 32);
      f32x4 w1 = *(const f32x4*)(wp + kk * 32 + 4);
      acc[n] = MFMA_BF16(af[kk], cvt8(w0, w1), acc[n]);
    }
  }
#pragma unroll
  for (int kk = 0; kk < 4; ++kk) {
    bf16x8 bf;
    if (np < 2) {
      const float* cp = Wc + np * 128 + kk * 32 + G * 8;
      f32x4 c0 = *(const f32x4*)cp;
      f32x4 c1 = *(const f32x4*)(cp + 4);
      bf = cvt8(c0, c1);
    } else {
#pragma unroll
      for (int j = 0; j < 8; ++j) bf[j] = (__bf16)0.0f;
    }
    accC = MFMA_BF16(af[kk], bf, accC);
  }

  const float a20 = Wcat[2], a21 = Wcat[3];
  float wexp[4];
#pragma unroll
  for (int r = 0; r < 4; ++r) {
    float c0 = __shfl(accC[r], lane & 48);
    float c1 = __shfl(accC[r], (lane & 48) | 1);
    c0 = c0 > 0.f ? c0 : 0.2f * c0;
    c1 = c1 > 0.f ? c1 : 0.2f * c1;
    wexp[r] = __expf(c0 * a20 + c1 * a21);
  }

  const int t_rel = wv >> 1;
  const int g_store = (wv & 1) * 2 + (G >> 1);
  const int j0 = (G & 1) * 4;
#pragma unroll
  for (int n = 0; n < 8; ++n) {
    float bxv = bx[n * 16 + np];
    __bf16 v[4];
#pragma unroll
    for (int r = 0; r < 4; ++r) v[r] = (__bf16)(wexp[r] * (acc[n][r] + bxv));
    *(__bf16*)&lds[(t_rel * 9 + n) * 512 + g_store * 128 + np * 8 + j0 + 0] = v[0];
    lds[(t_rel * 9 + n) * 512 + g_store * 128 + np * 8 + j0 + 1] = v[1];
    lds[(t_rel * 9 + n) * 512 + g_store * 128 + np * 8 + j0 + 2] = v[2];
    lds[(t_rel * 9 + n) * 512 + g_store * 128 + np * 8 + j0 + 3] = v[3];
  }
  {
#pragma unroll
    for (int r = 0; r < 4; ++r)
      lds[(t_rel * 9 + 8) * 512 + g_store * 128 + np * 8 + j0 + r] =
          (np == 0) ? (__bf16)wexp[r] : (__bf16)0.0f;
  }
  __syncthreads();
  __bf16* dst = u + ((size_t)(b * 64 + mt * 2)) * 9 * 512;
  for (int s = threadIdx.x; s < 1152; s += 256)
    ((i32x4*)dst)[s] = ((const i32x4*)lds)[s];
}

// ---------------------------------------------------------------------------
// Kernel P: mask (i32 0/1) -> bf16 {1.0, 0.0} in EXACT mfma A-frag order.
// Frag for (b, rt-block of 32 rows, t, mi): lane l holds row mi*16+(l&15),
// k = t*32 + (l>>4)*8 + j  (j=0..7, low bf16 of dword = even j).
// Flat: Abuf[ (((b*64+rt)*64 + t)*2 + mi)*512 + l*8 + j ].  134 MB -> 67 MB.
// ---------------------------------------------------------------------------
__global__ __launch_bounds__(256) void packA_kernel(
    const int* __restrict__ mask, __bf16* __restrict__ Abuf)
{
  __shared__ int sm[32 * 129];  // +1 pad: bank = (row+col)%32
  const int b = blockIdx.x & 7, rt = blockIdx.x >> 3;  // 8 x 64
  const int tid = threadIdx.x;
  const int* mbase = mask + ((size_t)b * 2048 + rt * 32) * 2048;
  __bf16* obase = Abuf + (size_t)(b * 64 + rt) * 64 * 1024;

  const int row_r = tid >> 3;        // read row 0..31
  const int cb8 = (tid & 7) * 16;    // 16 i32 per thread per chunk
  const int f = tid >> 5;            // frag 0..7 = (tk, mi)
  const int tk = f >> 1, mi = f & 1;

  for (int ch = 0; ch < 16; ++ch) {  // 16 chunks of 128 cols
    const int* rp = mbase + (size_t)row_r * 2048 + ch * 128 + cb8;
    i32x4 v0 = *(const i32x4*)rp;
    i32x4 v1 = *(const i32x4*)(rp + 4);
    i32x4 v2 = *(const i32x4*)(rp + 8);
    i32x4 v3 = *(const i32x4*)(rp + 12);
    __syncthreads();  // prior chunk's readers done
    *(i32x4*)&sm[row_r * 129 + cb8 + 0]  = v0;
    *(i32x4*)&sm[row_r * 129 + cb8 + 4]  = v1;
    *(i32x4*)&sm[row_r * 129 + cb8 + 8]  = v2;
    *(i32x4*)&sm[row_r * 129 + cb8 + 12] = v3;
    __syncthreads();
#pragma unroll
    for (int h = 0; h < 2; ++h) {
      const int l = (tid & 31) + h * 32;
      const int row = mi * 16 + (l & 15);
      const int col = tk * 32 + (l >> 4) * 8;
      u32 P[4];
#pragma unroll
      for (int q = 0; q < 4; ++q) {
        u32 lo = sm[row * 129 + col + 2 * q]     ? 0x3F80u : 0u;
        u32 hi = sm[row * 129 + col + 2 * q + 1] ? 0x3F800000u : 0u;
        P[q] = lo | hi;
      }
      __bf16* op = obase + ((size_t)(ch * 4 + tk) * 2 + mi) * 512 + l * 8;
      *(i32x4*)op = *(const i32x4*)P;
    }
  }
}

// ---------------------------------------------------------------------------
// Kernel B v10: VALU-free K-loop. Per iter (BK=32): 5 ds_read_b128 + 6 MFMA +
// addr only. Ring of 4 bufs ([A 2K][u 9K] = 11K); stage = global_load_lds
// only: wave0 {A0,A1,u0}, wave1 {u1-3}, wave2 {u4-6}, wave3 {u7,u8}.
// Counted vmcnt (per-wave L: 3,3,3,2 -> steady vmcnt 2L), raw s_barrier,
// never drains to 0 until tail. Den = 9th u tile -> MFMA, epilogue as R7.
// ---------------------------------------------------------------------------
__global__ __launch_bounds__(256) void attn_kernel(
    const __bf16* __restrict__ Abuf, const __bf16* __restrict__ u,
    float* __restrict__ out)
{
  __shared__ char smem[4 * 11264];  // 44 KB
  const int b = blockIdx.x & 7, rt = blockIdx.x >> 3;  // 8 x 64 (batch->XCD)
  const int wv = threadIdx.x >> 6, lane = threadIdx.x & 63;
  const int np = lane & 15, G = lane >> 4;
  const int row0 = rt * 32;
  const int n0 = wv * 2, n1 = n0 + 1;

  const char* gA = (const char*)Abuf + (size_t)(b * 64 + rt) * 64 * 2048;
  const char* gu = (const char*)u + (size_t)b * 64 * 9216;

  f32x4 acc[2][3];  // [mi][n0, n1, den]
#pragma unroll
  for (int mi = 0; mi < 2; ++mi)
#pragma unroll
    for (int n = 0; n < 3; ++n) { acc[mi][n][0] = 0.f; acc[mi][n][1] = 0.f; acc[mi][n][2] = 0.f; acc[mi][n][3] = 0.f; }

#define STAGE(it, nb)                                                          \
  do {                                                                         \
    char* dst = smem + (nb) * 11264;                                           \
    if (wv == 0) {                                                             \
      const char* ga = gA + (size_t)(it) * 2048 + lane * 16;                   \
      GLOAD_LDS16(ga, dst);                                                    \
      GLOAD_LDS16(ga + 1024, dst + 1024);                                      \
      GLOAD_LDS16(gu + (size_t)(it) * 9216 + lane * 16, dst + 2048);           \
    } else if (wv == 3) {                                                      \
      const char* gp = gu + (size_t)(it) * 9216 + 7 * 1024 + lane * 16;        \
      GLOAD_LDS16(gp, dst + 2048 + 7 * 1024);                                  \
      GLOAD_LDS16(gp + 1024, dst + 2048 + 8 * 1024);                           \
    } else {                                                                   \
      const char* gp = gu + (size_t)(it) * 9216 + (wv * 3 - 2) * 1024 + lane * 16; \
      GLOAD_LDS16(gp, dst + 2048 + (wv * 3 - 2) * 1024);                       \
      GLOAD_LDS16(gp + 1024, dst + 2048 + (wv * 3 - 1) * 1024);                \
      GLOAD_LDS16(gp + 2048, dst + 2048 + (wv * 3) * 1024);                    \
    }                                                                          \
  } while (0)

#define CONSUME(nb)                                                            \
  do {                                                                         \
    const char* buf = smem + (nb) * 11264;                                     \
    bf16x8 A0 = *(const bf16x8*)(buf + lane * 16);                             \
    bf16x8 A1 = *(const bf16x8*)(buf + 1024 + lane * 16);                      \
    const char* ub = buf + 2048;                                               \
    bf16x8 U0 = *(const bf16x8*)(ub + n0 * 1024 + lane * 16);                  \
    bf16x8 U1 = *(const bf16x8*)(ub + n1 * 1024 + lane * 16);                  \
    bf16x8 UD = *(const bf16x8*)(ub + 8 * 1024 + lane * 16);                   \
    acc[0][0] = MFMA_BF16(A0, U0, acc[0][0]);                                  \
    acc[0][1] = MFMA_BF16(A0, U1, acc[0][1]);                                  \
    acc[0][2] = MFMA_BF16(A0, UD, acc[0][2]);                                  \
    acc[1][0] = MFMA_BF16(A1, U0, acc[1][0]);                                  \
    acc[1][1] = MFMA_BF16(A1, U1, acc[1][1]);                                  \
    acc[1][2] = MFMA_BF16(A1, UD, acc[1][2]);                                  \
  } while (0)

  STAGE(0, 0); STAGE(1, 1); STAGE(2, 2);
  const int wvu = __builtin_amdgcn_readfirstlane(wv);

  for (int it = 0; it <= 61; ++it) {
    if (wvu == 3) asm volatile("s_waitcnt vmcnt(4)" ::: "memory");
    else          asm volatile("s_waitcnt vmcnt(6)" ::: "memory");
    __builtin_amdgcn_s_barrier();
    CONSUME(it & 3);
    if (it <= 60) STAGE(it + 3, (it + 3) & 3);
  }
  if (wvu == 3) asm volatile("s_waitcnt vmcnt(2)" ::: "memory");
  else          asm volatile("s_waitcnt vmcnt(3)" ::: "memory");
  __builtin_amdgcn_s_barrier();
  CONSUME(62 & 3);
  asm volatile("s_waitcnt vmcnt(0)" ::: "memory");
  __builtin_amdgcn_s_barrier();
  CONSUME(63 & 3);
#undef STAGE
#undef CONSUME

  // epilogue (verified R1-R7): D row = mi*16+4G+r, col = n*16+np;
  // den = col 0 of tile-8 output, broadcast from lane (lane&48).
#pragma unroll
  for (int mi = 0; mi < 2; ++mi) {
#pragma unroll
    for (int r = 0; r < 4; ++r) {
      float den = __shfl(acc[mi][2][r], lane & 48);
      float inv = 1.0f / den;
      float* op = out + ((size_t)b * 2048 + row0 + mi * 16 + 4 * G + r) * 128 + np;
      op[n0 * 16] = acc[mi][0][r] * inv;
      op[n1 * 16] = acc[mi][1][r] * inv;
    }
  }
}

extern "C" void kernel_launch(void* const* d_in, const int* in_sizes, int n_in,
                              void* d_out, int out_size, void* d_ws, size_t ws_size,
                              hipStream_t stream) {
  const float* x    = (const float*)d_in[0];
  const int*   mask = (const int*)d_in[1];
  // d_in[2] = Wr : unused (lr_row cancels in softmax over j)
  const float* Wc   = (const float*)d_in[3];
  const float* Wcat = (const float*)d_in[4];
  const float* Wx   = (const float*)d_in[5];
  const float* bx   = (const float*)d_in[6];
  float* out = (float*)d_out;

  // workspace: u 4.72 MB | Abuf 67.1 MB
  const size_t U_BYTES = (size_t)8 * 64 * 9 * 512 * 2;
  const size_t A_BYTES = (size_t)8 * 2048 * 2048 * 2;
  if (ws_size < U_BYTES + A_BYTES) return;
  __bf16* u    = (__bf16*)d_ws;
  __bf16* Abuf = (__bf16*)((char*)d_ws + U_BYTES);

  prep_kernel<<<256, 256, 0, stream>>>(x, Wc, Wcat, Wx, bx, u);
  packA_kernel<<<512, 256, 0, stream>>>(mask, Abuf);
  attn_kernel<<<512, 256, 0, stream>>>(Abuf, u, out);
}